// Round 7
// baseline (532.979 us; speedup 1.0000x reference)
//
#include <hip/hip_runtime.h>
#include <math.h>

#define HID 128
typedef unsigned int uint;
typedef unsigned short ushort;
typedef __attribute__((ext_vector_type(8))) short short8;
typedef __attribute__((ext_vector_type(4))) float floatx4;
typedef _Float16 h2 __attribute__((ext_vector_type(2)));

// ---------- bf16/fp16 helpers ----------
__device__ __forceinline__ ushort f2b(float f) {
  uint u = __float_as_uint(f);
  u += 0x7fffu + ((u >> 16) & 1u);
  return (ushort)(u >> 16);
}
__device__ __forceinline__ float b2f(ushort s) {
  return __uint_as_float(((uint)s) << 16);
}
__device__ __forceinline__ float blo(uint u) { return __uint_as_float(u << 16); }
__device__ __forceinline__ float bhi(uint u) { return __uint_as_float(u & 0xffff0000u); }
__device__ __forceinline__ ushort f2h(float f) {
  _Float16 h = (_Float16)f; ushort r; __builtin_memcpy(&r, &h, 2); return r;
}
__device__ __forceinline__ h2 u2h(uint u) { h2 r; __builtin_memcpy(&r, &u, 4); return r; }

__device__ __forceinline__ void gll16(const ushort* g, ushort* l) {
  __builtin_amdgcn_global_load_lds(
      (const __attribute__((address_space(1))) void*)g,
      (__attribute__((address_space(3))) void*)l, 16, 0, 0);
}

// Packed tile layout (128 rows x 32 k, bf16), 16B slot within tile:
//   slot = row*4 + (chunk ^ ((row>>1)&3)), chunk = k/8. Conflict-free staging+frags.
__device__ __forceinline__ size_t a_packed_us(int rr, int col) {
  int tm = rr >> 7, prow = rr & 127;
  int ptk = col >> 5, kin = col & 31;
  int sw = (kin >> 3) ^ ((prow >> 1) & 3);
  return (((size_t)tm * 4 + ptk) * 512 + (size_t)prow * 4 + sw) * 8 + (kin & 7);
}

// ================= prologue: pack x (3 types) + zero cnt + combine_rel ======
struct PackSeg { const float* X; ushort* out; int M, K, Ktiles, start; };
struct Prolog {
  PackSeg pk[3];
  int zstart, crwstart, total;
  int* cnt;
  const float *Wk, *bk, *Wv, *bv, *a_rel, *m_rel;
  float *Wk_rel, *bk_rel, *Wv_rel, *bv_rel;
};

__device__ void combine_rel_elem(const Prolog& P, int idx)
{
  int col  = idx & 127;
  int rest = idx >> 7;
  int row  = rest % 129;
  rest /= 129;
  int kv = rest & 1;
  int e  = rest >> 1;
  const int styp[4] = {0, 1, 1, 2};
  int i = styp[e];
  int h = col >> 4, j = col & 15;
  const float* Wsrc = kv ? P.Wv : P.Wk;
  const float* bsrc = kv ? P.bv : P.bk;
  const float* rel  = kv ? P.m_rel : P.a_rel;
  float acc = 0.f;
  if (row < 128) {
#pragma unroll
    for (int d = 0; d < 16; ++d)
      acc += Wsrc[(size_t)i * 16384 + (size_t)row * 128 + h * 16 + d] *
             rel[((e * 8 + h) * 16 + d) * 16 + j];
    (kv ? P.Wv_rel : P.Wk_rel)[(size_t)e * 16384 + (size_t)row * 128 + col] = acc;
  } else {
#pragma unroll
    for (int d = 0; d < 16; ++d)
      acc += bsrc[i * 128 + h * 16 + d] * rel[((e * 8 + h) * 16 + d) * 16 + j];
    (kv ? P.bv_rel : P.bk_rel)[e * 128 + col] = acc;
  }
}

__global__ __launch_bounds__(256)
void prologue(Prolog P)
{
  int gtid = blockIdx.x * 256 + threadIdx.x;
  if (gtid >= P.total) return;
  if (gtid >= P.crwstart) { combine_rel_elem(P, gtid - P.crwstart); return; }
  if (gtid >= P.zstart) { P.cnt[gtid - P.zstart] = 0; return; }
  int si = 0;
  if (gtid >= P.pk[2].start) si = 2;
  else if (gtid >= P.pk[1].start) si = 1;
  const PackSeg s = P.pk[si];
  int slot = gtid - s.start;
  int spm = s.Ktiles << 9;
  int tm = slot / spm, r2 = slot - tm * spm;
  int tk = r2 >> 9, o = r2 & 511;
  int row = o >> 2, sw = o & 3;
  int chunk = sw ^ ((row >> 1) & 3);
  int grow = tm * 128 + row;
  int gk = tk * 32 + chunk * 8;
  ushort tmp[8];
  if (grow < s.M && gk + 8 <= s.K) {
    const float* p = s.X + (size_t)grow * s.K + gk;
    float4 a = *(const float4*)p, b = *(const float4*)(p + 4);
    tmp[0] = f2b(a.x); tmp[1] = f2b(a.y); tmp[2] = f2b(a.z); tmp[3] = f2b(a.w);
    tmp[4] = f2b(b.x); tmp[5] = f2b(b.y); tmp[6] = f2b(b.z); tmp[7] = f2b(b.w);
  } else {
#pragma unroll
    for (int j = 0; j < 8; ++j) {
      int kk = gk + j;
      tmp[j] = (grow < s.M && kk < s.K) ? f2b(s.X[(size_t)grow * s.K + kk]) : (ushort)0;
    }
  }
  *(short8*)&s.out[(size_t)slot * 8] = *(short8*)tmp;
}

// ================= weight prep: pure layout conversion to packed-B ==========
struct WBlk { const float* src; ushort* dst; int K; int start; };
struct PrepW {
  WBlk b[18];
  int slot_total;
  const float* bsrc[11];
  float* bdst;
  int total;
};

__global__ __launch_bounds__(256)
void prep_weights(PrepW P)
{
  int gtid = blockIdx.x * 256 + threadIdx.x;
  if (gtid >= P.total) return;
  if (gtid >= P.slot_total) {
    int j2 = gtid - P.slot_total;
    P.bdst[j2] = P.bsrc[j2 >> 7][j2 & 127];
    return;
  }
  int si = 0;
#pragma unroll
  for (int k = 1; k < 18; ++k)
    if (gtid >= P.b[k].start) si = k;
  WBlk b = P.b[si];
  int s = gtid - b.start;
  int tk = s >> 9, o = s & 511;
  int c = o >> 2, swf = o & 3;
  int chunk = swf ^ ((c >> 1) & 3);
  int r0 = tk * 32 + chunk * 8;
  ushort tmp[8];
#pragma unroll
  for (int m = 0; m < 8; ++m) {
    int r = r0 + m;
    tmp[m] = (r < b.K) ? f2b(b.src[(size_t)r * 128 + c]) : (ushort)0;
  }
  *(short8*)&b.dst[(size_t)s * 8] = *(short8*)tmp;
}

// ================= CSR build ==============================================
__global__ void count_edges(const int* __restrict__ d0, const int* __restrict__ d1,
                            const int* __restrict__ d2, const int* __restrict__ d3,
                            int off0, int off1, int off2, int off3,
                            int* __restrict__ cnt, int E)
{
  int i = blockIdx.x * 256 + threadIdx.x;
  if (i >= 4 * E) return;
  int et = i / E, idx = i - et * E;
  const int* dp; int off;
  switch (et) {
    case 0: dp = d0; off = off0; break;
    case 1: dp = d1; off = off1; break;
    case 2: dp = d2; off = off2; break;
    default: dp = d3; off = off3; break;
  }
  atomicAdd(&cnt[off + dp[idx]], 1);
}

// --- 3-phase scan (multi-block) ---
__global__ __launch_bounds__(256)
void scan_blocks(const int* __restrict__ cnt, int* __restrict__ bsum, int n)
{
  __shared__ int ws[4];
  int t = threadIdx.x;
  int i = blockIdx.x * 1024 + t * 4;
  int s = 0;
  if (i + 4 <= n) {
    int4 x = *(const int4*)(cnt + i);
    s = x.x + x.y + x.z + x.w;
  } else {
    for (int j = 0; j < 4; ++j) if (i + j < n) s += cnt[i + j];
  }
#pragma unroll
  for (int o = 1; o < 64; o <<= 1) s += __shfl_xor(s, o, 64);
  if ((t & 63) == 0) ws[t >> 6] = s;
  __syncthreads();
  if (t == 0) bsum[blockIdx.x] = ws[0] + ws[1] + ws[2] + ws[3];
}

__global__ __launch_bounds__(256)
void scan_tops(int* __restrict__ bsum, int nb, int* __restrict__ starts, int n)
{
  __shared__ int ws[4];
  int t = threadIdx.x, lane = t & 63, w = t >> 6;
  int x = (t < nb) ? bsum[t] : 0;
  int v = x;
#pragma unroll
  for (int o = 1; o < 64; o <<= 1) {
    int y = __shfl_up(v, o, 64);
    if (lane >= o) v += y;
  }
  if (lane == 63) ws[w] = v;
  __syncthreads();
  int add = 0;
  for (int k = 0; k < w; ++k) add += ws[k];
  int excl = add + v - x;
  if (t < nb) bsum[t] = excl;
  if (t == nb - 1) starts[n] = excl + x;
}

__global__ __launch_bounds__(256)
void scan_final(const int* __restrict__ cnt, const int* __restrict__ bsum,
                int* __restrict__ starts, int* __restrict__ cursor, int n)
{
  __shared__ int ws[4];
  int t = threadIdx.x, lane = t & 63, w = t >> 6;
  int i = blockIdx.x * 1024 + t * 4;
  int4 x = make_int4(0, 0, 0, 0);
  bool full = (i + 4 <= n);
  if (full) x = *(const int4*)(cnt + i);
  else {
    if (i < n)     x.x = cnt[i];
    if (i + 1 < n) x.y = cnt[i + 1];
    if (i + 2 < n) x.z = cnt[i + 2];
  }
  int s = x.x + x.y + x.z + x.w;
  int v = s;
#pragma unroll
  for (int o = 1; o < 64; o <<= 1) {
    int y = __shfl_up(v, o, 64);
    if (lane >= o) v += y;
  }
  if (lane == 63) ws[w] = v;
  __syncthreads();
  int add = bsum[blockIdx.x];
  for (int k = 0; k < w; ++k) add += ws[k];
  int e0 = add + v - s;
  int4 st;
  st.x = e0; st.y = e0 + x.x; st.z = st.y + x.y; st.w = st.z + x.z;
  if (full) {
    *(int4*)(starts + i) = st;
    *(int4*)(cursor + i) = st;
  } else {
    if (i < n)     { starts[i] = st.x;     cursor[i] = st.x; }
    if (i + 1 < n) { starts[i + 1] = st.y; cursor[i + 1] = st.y; }
    if (i + 2 < n) { starts[i + 2] = st.z; cursor[i + 2] = st.z; }
  }
}

__global__ void scatter_edges(const int* __restrict__ s0, const int* __restrict__ d0,
                              const int* __restrict__ s1, const int* __restrict__ d1,
                              const int* __restrict__ s2, const int* __restrict__ d2,
                              const int* __restrict__ s3, const int* __restrict__ d3,
                              int off0, int off1, int off2, int off3,
                              int* __restrict__ cursor, int* __restrict__ payload, int E)
{
  int i = blockIdx.x * 256 + threadIdx.x;
  if (i >= 4 * E) return;
  int et = i / E, idx = i - et * E;
  const int* sp; const int* dp; int off; int slot;
  switch (et) {
    case 0: sp = s0; dp = d0; off = off0; slot = 0; break;
    case 1: sp = s1; dp = d1; off = off1; slot = 0; break;
    case 2: sp = s2; dp = d2; off = off2; slot = 0; break;
    default: sp = s3; dp = d3; off = off3; slot = 1; break;
  }
  int pos = atomicAdd(&cursor[off + dp[idx]], 1);
  payload[pos] = sp[idx] | (slot << 28);
}

// ================= fused multi-segment MFMA GEMM ==========================
// epi: 0 = row-major 16-bit store (bf16, or fp16 for blocks in f16mask), unguarded
//      1 = fp32 row-major guarded
//      2 = skip-gate+relu fp32 guarded (skip from packed xs)
//      3 = skip-gate+relu bf16 PACKED store, unguarded
//      4 = plain bf16 PACKED store, unguarded
struct GemmSeg {
  const ushort* A; const ushort* B; const float* bias;
  void* out; const ushort* xsP;
  int Ktiles, ldo, Mreal, skip_idx, epi, NT, start, f16mask;
};
struct Gemm3 { GemmSeg s[3]; const float* skip; int nseg; };

__launch_bounds__(256)
__global__ void gemm_sched(Gemm3 g3)
{
  __shared__ __align__(16) ushort As[2][4096];
  __shared__ __align__(16) ushort Bs[2][4096];
  int bid = blockIdx.x;
  int si = 0;
  if (g3.nseg > 1 && bid >= g3.s[1].start)
    si = (g3.nseg > 2 && bid >= g3.s[2].start) ? 2 : 1;
  const GemmSeg sg = g3.s[si];
  int local = bid - sg.start;
  int tm = local / sg.NT, tn = local - tm * sg.NT;

  const int t = threadIdx.x;
  const int wave = t >> 6, lane = t & 63;
  const int wm = (wave >> 1) * 64, wn = (wave & 1) * 64;
  const int l16 = lane & 15, quad = lane >> 4;
  const int Ktiles = sg.Ktiles;

  const ushort* Abase = sg.A + (size_t)tm * Ktiles * 4096;
  const ushort* Bbase = sg.B + (size_t)tn * Ktiles * 4096;

  floatx4 acc[4][4];
#pragma unroll
  for (int i = 0; i < 4; ++i)
#pragma unroll
    for (int j = 0; j < 4; ++j) acc[i][j] = (floatx4){0.f, 0.f, 0.f, 0.f};

  auto stage = [&](int tk, int buf) {
#pragma unroll
    for (int j = 0; j < 4; ++j) {
      int c = wave * 4 + j;
      if (c < 8)
        gll16(Abase + (size_t)tk * 4096 + c * 512 + lane * 8, &As[buf][c * 512]);
      else
        gll16(Bbase + (size_t)tk * 4096 + (c - 8) * 512 + lane * 8, &Bs[buf][(c - 8) * 512]);
    }
  };

  stage(0, 0);
  __syncthreads();

  for (int tk = 0; tk < Ktiles; ++tk) {
    int buf = tk & 1;
    if (tk + 1 < Ktiles) stage(tk + 1, buf ^ 1);

    short8 af[4], bfr[4];
    const int swz = (quad ^ ((l16 >> 1) & 3)) * 8;
#pragma unroll
    for (int i = 0; i < 4; ++i) {
      af[i]  = *(const short8*)&As[buf][(wm + i * 16 + l16) * 32 + swz];
      bfr[i] = *(const short8*)&Bs[buf][(wn + i * 16 + l16) * 32 + swz];
    }
#pragma unroll
    for (int mi = 0; mi < 4; ++mi)
#pragma unroll
      for (int ni = 0; ni < 4; ++ni)
        acc[mi][ni] = __builtin_amdgcn_mfma_f32_16x16x32_bf16(
            af[mi], bfr[ni], acc[mi][ni], 0, 0, 0);
    __syncthreads();
  }

  const int epi = sg.epi;
  const int isf16 = (sg.f16mask >> tn) & 1;
  float g = 0.f, omg = 0.f;
  if (epi == 2 || epi == 3) {
    float s = g3.skip[sg.skip_idx];
    g = 1.f / (1.f + __expf(-s));
    omg = 1.f - g;
  }
#pragma unroll
  for (int ni = 0; ni < 4; ++ni) {
    int col = tn * 128 + wn + ni * 16 + l16;
    float bb = sg.bias[col];
#pragma unroll
    for (int mi = 0; mi < 4; ++mi) {
      int rloc = wm + mi * 16 + quad * 4;
#pragma unroll
      for (int r = 0; r < 4; ++r) {
        int prow = rloc + r;
        int rr = tm * 128 + prow;
        float v = acc[mi][ni][r] + bb;
        if (epi == 0) {
          ((ushort*)sg.out)[(size_t)rr * sg.ldo + col] = isf16 ? f2h(v) : f2b(v);
        } else if (epi == 1) {
          if (rr < sg.Mreal) ((float*)sg.out)[(size_t)rr * sg.ldo + col] = v;
        } else if (epi == 2) {
          if (rr < sg.Mreal) {
            float xo = b2f(sg.xsP[a_packed_us(rr, col)]);
            ((float*)sg.out)[(size_t)rr * sg.ldo + col] = fmaxf(g * v + omg * xo, 0.f);
          }
        } else if (epi == 3) {
          float xo = b2f(sg.xsP[a_packed_us(rr, col)]);
          ((ushort*)sg.out)[a_packed_us(rr, col)] = f2b(fmaxf(g * v + omg * xo, 0.f));
        } else {  // 4: plain packed bf16
          ((ushort*)sg.out)[a_packed_us(rr, col)] = f2b(v);
        }
      }
    }
  }
}

// ================= gather: one wave per dst node, 8 edges/iter ============
// 8 lanes per edge, ONE HEAD PER LANE (16 channels). q/k stored fp16 ->
// v_dot2_f32_f16; v bf16 -> fp32 accumulate. No cross-lane ops in loop.
// Unshifted softmax (logits small here; clamp 80; max-shift cancels in ratio).
struct GatherType {
  const ushort* q; const ushort* k0; const ushort* v0;
  const ushort* k1; const ushort* v1;
  const float* p0; const float* p1;
  ushort* agg;
  int ldq, ld0, ld1;
};
struct GatherDesc { GatherType ty[3]; int n0, n1; };

__launch_bounds__(256)
__global__ void gather_all(const int* __restrict__ starts, const int* __restrict__ payload,
                           GatherDesc gd, int Ntot)
{
  int wid = (blockIdx.x * 256 + threadIdx.x) >> 6;
  if (wid >= Ntot) return;
  int lane = threadIdx.x & 63;
  int g = lane >> 3, h = lane & 7;   // 8 edge-groups x 8 heads

  GatherType T;
  int d;
  if (wid < gd.n0)      { T = gd.ty[0]; d = wid; }
  else if (wid < gd.n1) { T = gd.ty[1]; d = wid - gd.n0; }
  else                  { T = gd.ty[2]; d = wid - gd.n1; }

  // q: fp16, 16 channels of head h
  const ushort* qp = T.q + (size_t)d * T.ldq + h * 16;
  uint4 qa = *(const uint4*)qp;
  uint4 qb = *(const uint4*)(qp + 8);
  h2 qh[8] = {u2h(qa.x), u2h(qa.y), u2h(qa.z), u2h(qa.w),
              u2h(qb.x), u2h(qb.y), u2h(qb.z), u2h(qb.w)};
  float sc0 = T.p0[h] * 0.25f, sc1 = T.p1[h] * 0.25f;

  int e0 = starts[wid], e1 = starts[wid + 1];
  float lsum = 0.f;
  float acc[16];
#pragma unroll
  for (int j = 0; j < 16; ++j) acc[j] = 0.f;

  for (int eb = e0; eb < e1; eb += 8) {
    int ee = eb + g;
    bool act = ee < e1;
    int p = payload[act ? ee : e0];
    int s = p & 0x0FFFFFFF;
    int slot = p >> 28;
    const ushort* kb = slot ? T.k1 : T.k0;
    const ushort* vb = slot ? T.v1 : T.v0;
    int ld = slot ? T.ld1 : T.ld0;
    size_t ro = (size_t)s * ld + h * 16;
    uint4 ka = *(const uint4*)(kb + ro);
    uint4 kc = *(const uint4*)(kb + ro + 8);
    uint4 va = *(const uint4*)(vb + ro);
    uint4 vc = *(const uint4*)(vb + ro + 8);
    float part = 0.f;
    part = __builtin_amdgcn_fdot2(qh[0], u2h(ka.x), part, false);
    part = __builtin_amdgcn_fdot2(qh[1], u2h(ka.y), part, false);
    part = __builtin_amdgcn_fdot2(qh[2], u2h(ka.z), part, false);
    part = __builtin_amdgcn_fdot2(qh[3], u2h(ka.w), part, false);
    part = __builtin_amdgcn_fdot2(qh[4], u2h(kc.x), part, false);
    part = __builtin_amdgcn_fdot2(qh[5], u2h(kc.y), part, false);
    part = __builtin_amdgcn_fdot2(qh[6], u2h(kc.z), part, false);
    part = __builtin_amdgcn_fdot2(qh[7], u2h(kc.w), part, false);
    float logit = part * (slot ? sc1 : sc0);
    float ex = __expf(fminf(logit, 80.f));
    ex = act ? ex : 0.f;
    lsum += ex;
    acc[0]  += ex * blo(va.x); acc[1]  += ex * bhi(va.x);
    acc[2]  += ex * blo(va.y); acc[3]  += ex * bhi(va.y);
    acc[4]  += ex * blo(va.z); acc[5]  += ex * bhi(va.z);
    acc[6]  += ex * blo(va.w); acc[7]  += ex * bhi(va.w);
    acc[8]  += ex * blo(vc.x); acc[9]  += ex * bhi(vc.x);
    acc[10] += ex * blo(vc.y); acc[11] += ex * bhi(vc.y);
    acc[12] += ex * blo(vc.z); acc[13] += ex * bhi(vc.z);
    acc[14] += ex * blo(vc.w); acc[15] += ex * bhi(vc.w);
  }

  // merge 8 edge-groups (lanes differ in bits 3,4,5)
  lsum += __shfl_xor(lsum, 8, 64);
  lsum += __shfl_xor(lsum, 16, 64);
  lsum += __shfl_xor(lsum, 32, 64);
#pragma unroll
  for (int j = 0; j < 16; ++j) {
    acc[j] += __shfl_xor(acc[j], 8, 64);
    acc[j] += __shfl_xor(acc[j], 16, 64);
    acc[j] += __shfl_xor(acc[j], 32, 64);
  }

  if (g == 0) {
    float inv = 1.f / (lsum + 1e-16f);
    uint o[4];
#pragma unroll
    for (int jj = 0; jj < 8; ++jj) {
      float xa = acc[2 * jj] * inv, xb = acc[2 * jj + 1] * inv;
      float ga = 0.5f * xa * (1.f + erff(xa * 0.70710678118654752f));
      float gb = 0.5f * xb * (1.f + erff(xb * 0.70710678118654752f));
      o[jj & 3] = ((uint)f2b(gb) << 16) | (uint)f2b(ga);
      if ((jj & 3) == 3) {
        // write 8-channel chunks c2 = (jj>>2)*... chunk pair for this half
        int c2 = jj >> 2;                 // 0: channels 0-7, 1: 8-15 of head h
        int tm = d >> 7, row = d & 127;
        int ptk = h >> 1;
        int kin = (h & 1) * 16 + c2 * 8;
        int chunk = kin >> 3;
        int sw = chunk ^ ((row >> 1) & 3);
        size_t us = (((size_t)tm * 4 + ptk) * 512 + (size_t)row * 4 + sw) * 8;
        *(uint4*)(T.agg + us) = make_uint4(o[0], o[1], o[2], o[3]);
      }
    }
  }
}

// ================= host =====================================================
extern "C" void kernel_launch(void* const* d_in, const int* in_sizes, int n_in,
                              void* d_out, int out_size, void* d_ws, size_t ws_size,
                              hipStream_t stream)
{
  const float* x_herb = (const float*)d_in[0];
  const float* x_ing  = (const float*)d_in[1];
  const float* x_tgt  = (const float*)d_in[2];
  const float* W_herb = (const float*)d_in[3];
  const float* b_herb = (const float*)d_in[4];
  const float* W_ing  = (const float*)d_in[5];
  const float* b_ing  = (const float*)d_in[6];
  const float* W_tgt  = (const float*)d_in[7];
  const float* b_tgt  = (const float*)d_in[8];
  const float* Wk     = (const float*)d_in[9];
  const float* bk     = (const float*)d_in[10];
  const float* Wq     = (const float*)d_in[11];
  const float* bq     = (const float*)d_in[12];
  const float* Wv     = (const float*)d_in[13];
  const float* bv     = (const float*)d_in[14];
  const float* a_rel  = (const float*)d_in[15];
  const float* m_rel  = (const float*)d_in[16];
  const float* p_rel  = (const float*)d_in[17];
  const float* Wa     = (const float*)d_in[18];
  const float* ba     = (const float*)d_in[19];
  const float* skip   = (const float*)d_in[20];
  const float* W_out  = (const float*)d_in[21];
  const float* b_out  = (const float*)d_in[22];
  const int* srcs[4] = {(const int*)d_in[23], (const int*)d_in[25],
                        (const int*)d_in[27], (const int*)d_in[29]};
  const int* dsts[4] = {(const int*)d_in[24], (const int*)d_in[26],
                        (const int*)d_in[28], (const int*)d_in[30]};

  const int Nh = in_sizes[0] / 400;
  const int Ni = in_sizes[1] / 300;
  const int Nt = in_sizes[2] / 200;
  const int E  = in_sizes[23];
  const int Ntot = Nh + Ni + Nt;

  const int MT_h = (Nh + 127) / 128, MT_i = (Ni + 127) / 128, MT_t = (Nt + 127) / 128;
  const int KT_h = 13, KT_i = 10, KT_t = 7;   // Kpad 416/320/224

  char* base = (char*)d_ws;
  size_t off = 0;
  auto A = [&](size_t bytes) -> void* {
    void* p = base + off; off += (bytes + 255) & ~(size_t)255; return p;
  };
  ushort* xp_h  = (ushort*)A((size_t)MT_h * KT_h * 8192);
  ushort* xp_i  = (ushort*)A((size_t)MT_i * KT_i * 8192);
  ushort* xp_t  = (ushort*)A((size_t)MT_t * KT_t * 8192);
  ushort* xsP_h = (ushort*)A((size_t)MT_h * 4 * 8192);
  ushort* xsP_i = (ushort*)A((size_t)MT_i * 4 * 8192);
  ushort* xsP_t = (ushort*)A((size_t)MT_t * 4 * 8192);
  ushort* fused_h = (ushort*)A((size_t)MT_h * 128 * 384 * 2);  // [q|k0|v0]
  ushort* fused_i = (ushort*)A((size_t)MT_i * 128 * 640 * 2);  // [q|k1|v1|k2|v2]
  ushort* fused_t = (ushort*)A((size_t)MT_t * 128 * 384 * 2);  // [q|k3|v3]
  ushort* aggp_h  = (ushort*)A((size_t)MT_h * 4 * 8192);
  ushort* aggp_i  = (ushort*)A((size_t)MT_i * 4 * 8192);
  ushort* aggp_t  = (ushort*)A((size_t)MT_t * 4 * 8192);
  ushort* htmp_p  = (ushort*)A((size_t)MT_h * 4 * 8192);
  float* Wk_rel = (float*)A(4 * 16384 * 4);
  float* Wv_rel = (float*)A(4 * 16384 * 4);
  float* bk_rel = (float*)A(4 * 128 * 4);
  float* bv_rel = (float*)A(4 * 128 * 4);
  ushort* Weff1_h = (ushort*)A((size_t)KT_h * 8192);
  ushort* Weff1_i = (ushort*)A((size_t)KT_i * 8192);
  ushort* Weff1_t = (ushort*)A((size_t)KT_t * 8192);
  ushort* Wcat_h = (ushort*)A((size_t)3 * 4 * 8192);
  ushort* Wcat_i = (ushort*)A((size_t)5 * 4 * 8192);
  ushort* Wcat_t = (ushort*)A((size_t)3 * 4 * 8192);
  float* bcat   = (float*)A(1408 * 4);
  ushort* Wa_t   = (ushort*)A((size_t)3 * 16384 * 2);
  ushort* Wout_t = (ushort*)A((size_t)16384 * 2);
  int* cnt     = (int*)A((size_t)Ntot * 4);
  int* starts  = (int*)A((size_t)(Ntot + 4) * 4);
  int* cursor  = (int*)A((size_t)Ntot * 4);
  int* bsum    = (int*)A(1024);
  int* payload = (int*)A((size_t)(4 * E + 8) * 4);
  (void)ws_size; (void)n_in;

  const int toff_h = 0, toff_i = Nh, toff_t = Nh + Ni;
  dim3 blk(256);

  // --- 1: prologue (pack x3 + zero cnt + combine_rel) ---
  int sl_h = MT_h * KT_h * 512, sl_i = MT_i * KT_i * 512, sl_t = MT_t * KT_t * 512;
  Prolog P;
  P.pk[0] = {x_herb, xp_h, Nh, 400, KT_h, 0};
  P.pk[1] = {x_ing,  xp_i, Ni, 300, KT_i, sl_h};
  P.pk[2] = {x_tgt,  xp_t, Nt, 200, KT_t, sl_h + sl_i};
  P.zstart = sl_h + sl_i + sl_t;
  P.crwstart = P.zstart + Ntot;
  P.total = P.crwstart + 4 * 2 * 129 * 128;
  P.cnt = cnt;
  P.Wk = Wk; P.bk = bk; P.Wv = Wv; P.bv = bv; P.a_rel = a_rel; P.m_rel = m_rel;
  P.Wk_rel = Wk_rel; P.bk_rel = bk_rel; P.Wv_rel = Wv_rel; P.bv_rel = bv_rel;
  prologue<<<(P.total + 255) / 256, blk, 0, stream>>>(P);

  // --- 2: CSR count + 3-phase scan + scatter ---
  int egrid4 = (4 * E + 255) / 256;
  count_edges<<<egrid4, blk, 0, stream>>>(dsts[0], dsts[1], dsts[2], dsts[3],
                                          toff_i, toff_h, toff_t, toff_i, cnt, E);
  int nb = (Ntot + 1023) / 1024;
  scan_blocks<<<nb, blk, 0, stream>>>(cnt, bsum, Ntot);
  scan_tops<<<1, blk, 0, stream>>>(bsum, nb, starts, Ntot);
  scan_final<<<nb, blk, 0, stream>>>(cnt, bsum, starts, cursor, Ntot);
  scatter_edges<<<egrid4, blk, 0, stream>>>(srcs[0], dsts[0], srcs[1], dsts[1],
                                            srcs[2], dsts[2], srcs[3], dsts[3],
                                            toff_i, toff_h, toff_t, toff_i,
                                            cursor, payload, E);

  // --- 3: weight prep (layout conversion only) ---
  PrepW PW;
  int st = 0;
  PW.b[0] = {W_herb, Weff1_h, 400, st}; st += KT_h * 512;
  PW.b[1] = {W_ing,  Weff1_i, 300, st}; st += KT_i * 512;
  PW.b[2] = {W_tgt,  Weff1_t, 200, st}; st += KT_t * 512;
  const float* csrc[11] = {
      Wq + 0 * 16384, Wk_rel + 0 * 16384, Wv_rel + 0 * 16384,
      Wq + 1 * 16384, Wk_rel + 1 * 16384, Wv_rel + 1 * 16384,
                      Wk_rel + 2 * 16384, Wv_rel + 2 * 16384,
      Wq + 2 * 16384, Wk_rel + 3 * 16384, Wv_rel + 3 * 16384};
  ushort* cdst[11] = {
      Wcat_h, Wcat_h + 16384, Wcat_h + 32768,
      Wcat_i, Wcat_i + 16384, Wcat_i + 32768, Wcat_i + 49152, Wcat_i + 65536,
      Wcat_t, Wcat_t + 16384, Wcat_t + 32768};
  for (int z = 0; z < 11; ++z) { PW.b[3 + z] = {csrc[z], cdst[z], 128, st}; st += 2048; }
  PW.b[14] = {Wa + 0 * 16384, Wa_t + 0 * 16384, 128, st}; st += 2048;
  PW.b[15] = {Wa + 1 * 16384, Wa_t + 1 * 16384, 128, st}; st += 2048;
  PW.b[16] = {Wa + 2 * 16384, Wa_t + 2 * 16384, 128, st}; st += 2048;
  PW.b[17] = {W_out, Wout_t, 128, st}; st += 2048;
  PW.slot_total = st;
  PW.bsrc[0] = bq + 0;   PW.bsrc[1] = bk_rel + 0;   PW.bsrc[2] = bv_rel + 0;
  PW.bsrc[3] = bq + 128; PW.bsrc[4] = bk_rel + 128; PW.bsrc[5] = bv_rel + 128;
                         PW.bsrc[6] = bk_rel + 256; PW.bsrc[7] = bv_rel + 256;
  PW.bsrc[8] = bq + 256; PW.bsrc[9] = bk_rel + 384; PW.bsrc[10] = bv_rel + 384;
  PW.bdst = bcat;
  PW.total = st + 1408;
  prep_weights<<<(PW.total + 255) / 256, blk, 0, stream>>>(PW);

  // --- 4: GEMM1  xs = x @ Win  (packed-A bf16 output) ---
  Gemm3 G1;
  G1.skip = skip; G1.nseg = 3;
  G1.s[0] = {xp_h, Weff1_h, b_herb, xsP_h, nullptr, KT_h, 0, 0, 0, 4, 1, 0};
  G1.s[1] = {xp_i, Weff1_i, b_ing,  xsP_i, nullptr, KT_i, 0, 0, 0, 4, 1, MT_h};
  G1.s[2] = {xp_t, Weff1_t, b_tgt,  xsP_t, nullptr, KT_t, 0, 0, 0, 4, 1, MT_h + MT_i};
  gemm_sched<<<MT_h + MT_i + MT_t, blk, 0, stream>>>(G1);

  // --- 5: GEMM2  [q|k|v] = xs @ Wcat (q/k fp16, v bf16; row-major) ---
  Gemm3 G2;
  G2.skip = skip; G2.nseg = 3;
  G2.s[0] = {xsP_h, Wcat_h, bcat + 0,    fused_h, nullptr, 4, 384, 0, 0, 0, 3, 0, 0x3};
  G2.s[1] = {xsP_i, Wcat_i, bcat + 384,  fused_i, nullptr, 4, 640, 0, 0, 0, 5, MT_h * 3, 0xB};
  G2.s[2] = {xsP_t, Wcat_t, bcat + 1024, fused_t, nullptr, 4, 384, 0, 0, 0, 3,
             MT_h * 3 + MT_i * 5, 0x3};
  gemm_sched<<<MT_h * 3 + MT_i * 5 + MT_t * 3, blk, 0, stream>>>(G2);

  // --- 6: gather attention (all types, one wave per node) ---
  GatherDesc GD;
  GD.n0 = Nh; GD.n1 = Nh + Ni;
  GD.ty[0] = {fused_h, fused_i + 128, fused_i + 256, fused_i + 128, fused_i + 256,
              p_rel + 1 * 8, p_rel + 1 * 8, aggp_h, 384, 640, 640};
  GD.ty[1] = {fused_i, fused_h + 128, fused_h + 256, fused_t + 128, fused_t + 256,
              p_rel + 0 * 8, p_rel + 3 * 8, aggp_i, 640, 384, 384};
  GD.ty[2] = {fused_t, fused_i + 384, fused_i + 512, fused_i + 384, fused_i + 512,
              p_rel + 2 * 8, p_rel + 2 * 8, aggp_t, 384, 640, 640};
  gather_all<<<(Ntot + 3) / 4, blk, 0, stream>>>(starts, payload, GD, Ntot);

  // --- 7: fused epilogue GEMMs (Wa per type; skip from packed xs) ---
  float* outp = (float*)d_out;
  float* out_herb = outp;
  float* out_ing  = outp + (size_t)Nh * HID;
  float* out_tgt  = outp + (size_t)(Nh + Ni) * HID;
  Gemm3 GE;
  GE.skip = skip; GE.nseg = 3;
  GE.s[0] = {aggp_h, Wa_t + 0 * 16384, ba + 0 * 128, htmp_p, xsP_h,
             4, 0, 0, 0, 3, 1, 0};
  GE.s[1] = {aggp_i, Wa_t + 1 * 16384, ba + 1 * 128, out_ing, xsP_i,
             4, 128, Ni, 1, 2, 1, MT_h};
  GE.s[2] = {aggp_t, Wa_t + 2 * 16384, ba + 2 * 128, out_tgt, xsP_t,
             4, 128, Nt, 2, 2, 1, MT_h + MT_i};
  gemm_sched<<<MT_h + MT_i + MT_t, blk, 0, stream>>>(GE);

  // --- 8: final herb GEMM ---
  Gemm3 GF;
  GF.skip = skip; GF.nseg = 1;
  GF.s[0] = {htmp_p, Wout_t, b_out, out_herb, nullptr, 4, 128, Nh, 0, 1, 1, 0};
  GF.s[1] = GF.s[0]; GF.s[2] = GF.s[0];
  gemm_sched<<<MT_h, blk, 0, stream>>>(GF);
  (void)out_size;
}

// Round 8
// 522.244 us; speedup vs baseline: 1.0206x; 1.0206x over previous
//
#include <hip/hip_runtime.h>
#include <math.h>

#define HID 128
typedef unsigned int uint;
typedef unsigned short ushort;
typedef __attribute__((ext_vector_type(8))) short short8;
typedef __attribute__((ext_vector_type(4))) float floatx4;

// ---------- bf16 helpers ----------
__device__ __forceinline__ ushort f2b(float f) {
  uint u = __float_as_uint(f);
  u += 0x7fffu + ((u >> 16) & 1u);
  return (ushort)(u >> 16);
}
__device__ __forceinline__ float b2f(ushort s) {
  return __uint_as_float(((uint)s) << 16);
}
__device__ __forceinline__ float blo(uint u) { return __uint_as_float(u << 16); }
__device__ __forceinline__ float bhi(uint u) { return __uint_as_float(u & 0xffff0000u); }

__device__ __forceinline__ void gll16(const ushort* g, ushort* l) {
  __builtin_amdgcn_global_load_lds(
      (const __attribute__((address_space(1))) void*)g,
      (__attribute__((address_space(3))) void*)l, 16, 0, 0);
}

// Packed tile layout (128 rows x 32 k, bf16), 16B slot within tile:
//   slot = row*4 + (chunk ^ ((row>>1)&3)), chunk = k/8. Conflict-free staging+frags.
__device__ __forceinline__ size_t a_packed_us(int rr, int col) {
  int tm = rr >> 7, prow = rr & 127;
  int ptk = col >> 5, kin = col & 31;
  int sw = (kin >> 3) ^ ((prow >> 1) & 3);
  return (((size_t)tm * 4 + ptk) * 512 + (size_t)prow * 4 + sw) * 8 + (kin & 7);
}

// ================= prologue: pack x (3 types) + zero cnt + combine_rel ======
struct PackSeg { const float* X; ushort* out; int M, K, Ktiles, start; };
struct Prolog {
  PackSeg pk[3];
  int zstart, crwstart, total;
  int* cnt;
  const float *Wk, *bk, *Wv, *bv, *a_rel, *m_rel;
  float *Wk_rel, *bk_rel, *Wv_rel, *bv_rel;
};

__device__ void combine_rel_elem(const Prolog& P, int idx)
{
  int col  = idx & 127;
  int rest = idx >> 7;
  int row  = rest % 129;
  rest /= 129;
  int kv = rest & 1;
  int e  = rest >> 1;
  const int styp[4] = {0, 1, 1, 2};
  int i = styp[e];
  int h = col >> 4, j = col & 15;
  const float* Wsrc = kv ? P.Wv : P.Wk;
  const float* bsrc = kv ? P.bv : P.bk;
  const float* rel  = kv ? P.m_rel : P.a_rel;
  float acc = 0.f;
  if (row < 128) {
#pragma unroll
    for (int d = 0; d < 16; ++d)
      acc += Wsrc[(size_t)i * 16384 + (size_t)row * 128 + h * 16 + d] *
             rel[((e * 8 + h) * 16 + d) * 16 + j];
    (kv ? P.Wv_rel : P.Wk_rel)[(size_t)e * 16384 + (size_t)row * 128 + col] = acc;
  } else {
#pragma unroll
    for (int d = 0; d < 16; ++d)
      acc += bsrc[i * 128 + h * 16 + d] * rel[((e * 8 + h) * 16 + d) * 16 + j];
    (kv ? P.bv_rel : P.bk_rel)[e * 128 + col] = acc;
  }
}

__global__ __launch_bounds__(256)
void prologue(Prolog P)
{
  int gtid = blockIdx.x * 256 + threadIdx.x;
  if (gtid >= P.total) return;
  if (gtid >= P.crwstart) { combine_rel_elem(P, gtid - P.crwstart); return; }
  if (gtid >= P.zstart) { P.cnt[gtid - P.zstart] = 0; return; }
  int si = 0;
  if (gtid >= P.pk[2].start) si = 2;
  else if (gtid >= P.pk[1].start) si = 1;
  const PackSeg s = P.pk[si];
  int slot = gtid - s.start;
  int spm = s.Ktiles << 9;
  int tm = slot / spm, r2 = slot - tm * spm;
  int tk = r2 >> 9, o = r2 & 511;
  int row = o >> 2, sw = o & 3;
  int chunk = sw ^ ((row >> 1) & 3);
  int grow = tm * 128 + row;
  int gk = tk * 32 + chunk * 8;
  ushort tmp[8];
  if (grow < s.M && gk + 8 <= s.K) {
    const float* p = s.X + (size_t)grow * s.K + gk;
    float4 a = *(const float4*)p, b = *(const float4*)(p + 4);
    tmp[0] = f2b(a.x); tmp[1] = f2b(a.y); tmp[2] = f2b(a.z); tmp[3] = f2b(a.w);
    tmp[4] = f2b(b.x); tmp[5] = f2b(b.y); tmp[6] = f2b(b.z); tmp[7] = f2b(b.w);
  } else {
#pragma unroll
    for (int j = 0; j < 8; ++j) {
      int kk = gk + j;
      tmp[j] = (grow < s.M && kk < s.K) ? f2b(s.X[(size_t)grow * s.K + kk]) : (ushort)0;
    }
  }
  *(short8*)&s.out[(size_t)slot * 8] = *(short8*)tmp;
}

// ================= weight prep: pure layout conversion to packed-B ==========
struct WBlk { const float* src; ushort* dst; int K; int start; };
struct PrepW {
  WBlk b[18];
  int slot_total;
  const float* bsrc[11];
  float* bdst;
  int total;
};

__global__ __launch_bounds__(256)
void prep_weights(PrepW P)
{
  int gtid = blockIdx.x * 256 + threadIdx.x;
  if (gtid >= P.total) return;
  if (gtid >= P.slot_total) {
    int j2 = gtid - P.slot_total;
    P.bdst[j2] = P.bsrc[j2 >> 7][j2 & 127];
    return;
  }
  int si = 0;
#pragma unroll
  for (int k = 1; k < 18; ++k)
    if (gtid >= P.b[k].start) si = k;
  WBlk b = P.b[si];
  int s = gtid - b.start;
  int tk = s >> 9, o = s & 511;
  int c = o >> 2, swf = o & 3;
  int chunk = swf ^ ((c >> 1) & 3);
  int r0 = tk * 32 + chunk * 8;
  ushort tmp[8];
#pragma unroll
  for (int m = 0; m < 8; ++m) {
    int r = r0 + m;
    tmp[m] = (r < b.K) ? f2b(b.src[(size_t)r * 128 + c]) : (ushort)0;
  }
  *(short8*)&b.dst[(size_t)s * 8] = *(short8*)tmp;
}

// ================= CSR build ==============================================
__global__ void count_edges(const int* __restrict__ d0, const int* __restrict__ d1,
                            const int* __restrict__ d2, const int* __restrict__ d3,
                            int off0, int off1, int off2, int off3,
                            int* __restrict__ cnt, int E)
{
  int i = blockIdx.x * 256 + threadIdx.x;
  if (i >= 4 * E) return;
  int et = i / E, idx = i - et * E;
  const int* dp; int off;
  switch (et) {
    case 0: dp = d0; off = off0; break;
    case 1: dp = d1; off = off1; break;
    case 2: dp = d2; off = off2; break;
    default: dp = d3; off = off3; break;
  }
  atomicAdd(&cnt[off + dp[idx]], 1);
}

// --- 3-phase scan (multi-block) ---
__global__ __launch_bounds__(256)
void scan_blocks(const int* __restrict__ cnt, int* __restrict__ bsum, int n)
{
  __shared__ int ws[4];
  int t = threadIdx.x;
  int i = blockIdx.x * 1024 + t * 4;
  int s = 0;
  if (i + 4 <= n) {
    int4 x = *(const int4*)(cnt + i);
    s = x.x + x.y + x.z + x.w;
  } else {
    for (int j = 0; j < 4; ++j) if (i + j < n) s += cnt[i + j];
  }
#pragma unroll
  for (int o = 1; o < 64; o <<= 1) s += __shfl_xor(s, o, 64);
  if ((t & 63) == 0) ws[t >> 6] = s;
  __syncthreads();
  if (t == 0) bsum[blockIdx.x] = ws[0] + ws[1] + ws[2] + ws[3];
}

__global__ __launch_bounds__(256)
void scan_tops(int* __restrict__ bsum, int nb, int* __restrict__ starts, int n)
{
  __shared__ int ws[4];
  int t = threadIdx.x, lane = t & 63, w = t >> 6;
  int x = (t < nb) ? bsum[t] : 0;
  int v = x;
#pragma unroll
  for (int o = 1; o < 64; o <<= 1) {
    int y = __shfl_up(v, o, 64);
    if (lane >= o) v += y;
  }
  if (lane == 63) ws[w] = v;
  __syncthreads();
  int add = 0;
  for (int k = 0; k < w; ++k) add += ws[k];
  int excl = add + v - x;
  if (t < nb) bsum[t] = excl;
  if (t == nb - 1) starts[n] = excl + x;
}

__global__ __launch_bounds__(256)
void scan_final(const int* __restrict__ cnt, const int* __restrict__ bsum,
                int* __restrict__ starts, int* __restrict__ cursor, int n)
{
  __shared__ int ws[4];
  int t = threadIdx.x, lane = t & 63, w = t >> 6;
  int i = blockIdx.x * 1024 + t * 4;
  int4 x = make_int4(0, 0, 0, 0);
  bool full = (i + 4 <= n);
  if (full) x = *(const int4*)(cnt + i);
  else {
    if (i < n)     x.x = cnt[i];
    if (i + 1 < n) x.y = cnt[i + 1];
    if (i + 2 < n) x.z = cnt[i + 2];
  }
  int s = x.x + x.y + x.z + x.w;
  int v = s;
#pragma unroll
  for (int o = 1; o < 64; o <<= 1) {
    int y = __shfl_up(v, o, 64);
    if (lane >= o) v += y;
  }
  if (lane == 63) ws[w] = v;
  __syncthreads();
  int add = bsum[blockIdx.x];
  for (int k = 0; k < w; ++k) add += ws[k];
  int e0 = add + v - s;
  int4 st;
  st.x = e0; st.y = e0 + x.x; st.z = st.y + x.y; st.w = st.z + x.z;
  if (full) {
    *(int4*)(starts + i) = st;
    *(int4*)(cursor + i) = st;
  } else {
    if (i < n)     { starts[i] = st.x;     cursor[i] = st.x; }
    if (i + 1 < n) { starts[i + 1] = st.y; cursor[i + 1] = st.y; }
    if (i + 2 < n) { starts[i + 2] = st.z; cursor[i + 2] = st.z; }
  }
}

__global__ void scatter_edges(const int* __restrict__ s0, const int* __restrict__ d0,
                              const int* __restrict__ s1, const int* __restrict__ d1,
                              const int* __restrict__ s2, const int* __restrict__ d2,
                              const int* __restrict__ s3, const int* __restrict__ d3,
                              int off0, int off1, int off2, int off3,
                              int* __restrict__ cursor, int* __restrict__ payload, int E)
{
  int i = blockIdx.x * 256 + threadIdx.x;
  if (i >= 4 * E) return;
  int et = i / E, idx = i - et * E;
  const int* sp; const int* dp; int off; int slot;
  switch (et) {
    case 0: sp = s0; dp = d0; off = off0; slot = 0; break;
    case 1: sp = s1; dp = d1; off = off1; slot = 0; break;
    case 2: sp = s2; dp = d2; off = off2; slot = 0; break;
    default: sp = s3; dp = d3; off = off3; slot = 1; break;
  }
  int pos = atomicAdd(&cursor[off + dp[idx]], 1);
  payload[pos] = sp[idx] | (slot << 28);
}

// ================= fused multi-segment MFMA GEMM ==========================
// epi: 0 = bf16 row-major (unguarded, padded out)
//      1 = fp32 row-major guarded
//      2 = skip-gate+relu fp32 guarded (skip from packed xs)
//      3 = skip-gate+relu bf16 PACKED store, unguarded
//      4 = plain bf16 PACKED store, unguarded
struct GemmSeg {
  const ushort* A; const ushort* B; const float* bias;
  void* out; const ushort* xsP;
  int Ktiles, ldo, Mreal, skip_idx, epi, NT, start;
};
struct Gemm3 { GemmSeg s[3]; const float* skip; int nseg; };

__launch_bounds__(256)
__global__ void gemm_sched(Gemm3 g3)
{
  __shared__ __align__(16) ushort As[2][4096];
  __shared__ __align__(16) ushort Bs[2][4096];
  int bid = blockIdx.x;
  int si = 0;
  if (g3.nseg > 1 && bid >= g3.s[1].start)
    si = (g3.nseg > 2 && bid >= g3.s[2].start) ? 2 : 1;
  const GemmSeg sg = g3.s[si];
  int local = bid - sg.start;
  int tm = local / sg.NT, tn = local - tm * sg.NT;

  const int t = threadIdx.x;
  const int wave = t >> 6, lane = t & 63;
  const int wm = (wave >> 1) * 64, wn = (wave & 1) * 64;
  const int l16 = lane & 15, quad = lane >> 4;
  const int Ktiles = sg.Ktiles;

  const ushort* Abase = sg.A + (size_t)tm * Ktiles * 4096;
  const ushort* Bbase = sg.B + (size_t)tn * Ktiles * 4096;

  floatx4 acc[4][4];
#pragma unroll
  for (int i = 0; i < 4; ++i)
#pragma unroll
    for (int j = 0; j < 4; ++j) acc[i][j] = (floatx4){0.f, 0.f, 0.f, 0.f};

  auto stage = [&](int tk, int buf) {
#pragma unroll
    for (int j = 0; j < 4; ++j) {
      int c = wave * 4 + j;
      if (c < 8)
        gll16(Abase + (size_t)tk * 4096 + c * 512 + lane * 8, &As[buf][c * 512]);
      else
        gll16(Bbase + (size_t)tk * 4096 + (c - 8) * 512 + lane * 8, &Bs[buf][(c - 8) * 512]);
    }
  };

  stage(0, 0);
  __syncthreads();

  for (int tk = 0; tk < Ktiles; ++tk) {
    int buf = tk & 1;
    if (tk + 1 < Ktiles) stage(tk + 1, buf ^ 1);

    short8 af[4], bfr[4];
    const int swz = (quad ^ ((l16 >> 1) & 3)) * 8;
#pragma unroll
    for (int i = 0; i < 4; ++i) {
      af[i]  = *(const short8*)&As[buf][(wm + i * 16 + l16) * 32 + swz];
      bfr[i] = *(const short8*)&Bs[buf][(wn + i * 16 + l16) * 32 + swz];
    }
#pragma unroll
    for (int mi = 0; mi < 4; ++mi)
#pragma unroll
      for (int ni = 0; ni < 4; ++ni)
        acc[mi][ni] = __builtin_amdgcn_mfma_f32_16x16x32_bf16(
            af[mi], bfr[ni], acc[mi][ni], 0, 0, 0);
    __syncthreads();
  }

  const int epi = sg.epi;
  float g = 0.f, omg = 0.f;
  if (epi == 2 || epi == 3) {
    float s = g3.skip[sg.skip_idx];
    g = 1.f / (1.f + __expf(-s));
    omg = 1.f - g;
  }
#pragma unroll
  for (int ni = 0; ni < 4; ++ni) {
    int col = tn * 128 + wn + ni * 16 + l16;
    float bb = sg.bias[col];
#pragma unroll
    for (int mi = 0; mi < 4; ++mi) {
      int rloc = wm + mi * 16 + quad * 4;
#pragma unroll
      for (int r = 0; r < 4; ++r) {
        int prow = rloc + r;
        int rr = tm * 128 + prow;
        float v = acc[mi][ni][r] + bb;
        if (epi == 0) {
          ((ushort*)sg.out)[(size_t)rr * sg.ldo + col] = f2b(v);
        } else if (epi == 1) {
          if (rr < sg.Mreal) ((float*)sg.out)[(size_t)rr * sg.ldo + col] = v;
        } else if (epi == 2) {
          if (rr < sg.Mreal) {
            float xo = b2f(sg.xsP[a_packed_us(rr, col)]);
            ((float*)sg.out)[(size_t)rr * sg.ldo + col] = fmaxf(g * v + omg * xo, 0.f);
          }
        } else if (epi == 3) {
          float xo = b2f(sg.xsP[a_packed_us(rr, col)]);
          ((ushort*)sg.out)[a_packed_us(rr, col)] = f2b(fmaxf(g * v + omg * xo, 0.f));
        } else {  // 4: plain packed bf16
          ((ushort*)sg.out)[a_packed_us(rr, col)] = f2b(v);
        }
      }
    }
  }
}

// ================= gather: one wave per dst node, 2x4 edges/iter ==========
// 16 lanes per edge, 8 channels/lane; TWO independent 4-edge batches per
// iteration so 4x16B loads are in flight before either batch is consumed
// (the gather is HBM-latency/parallelism bound). Unshifted softmax (logits
// ~N(0,1) here; clamp 80; max-shift cancels in the alpha ratio).
struct GatherType {
  const ushort* q; const ushort* k0; const ushort* v0;
  const ushort* k1; const ushort* v1;
  const float* p0; const float* p1;
  ushort* agg;
  int ldq, ld0, ld1;
};
struct GatherDesc { GatherType ty[3]; int n0, n1; };

__launch_bounds__(256)
__global__ void gather_all(const int* __restrict__ starts, const int* __restrict__ payload,
                           GatherDesc gd, int Ntot)
{
  int wid = (blockIdx.x * 256 + threadIdx.x) >> 6;
  if (wid >= Ntot) return;
  int lane = threadIdx.x & 63;
  int g = lane >> 4, l = lane & 15, h = l >> 1;

  GatherType T;
  int d;
  if (wid < gd.n0)      { T = gd.ty[0]; d = wid; }
  else if (wid < gd.n1) { T = gd.ty[1]; d = wid - gd.n0; }
  else                  { T = gd.ty[2]; d = wid - gd.n1; }

  uint4 qv = *(const uint4*)(T.q + (size_t)d * T.ldq + l * 8);
  float qf0 = blo(qv.x), qf1 = bhi(qv.x), qf2 = blo(qv.y), qf3 = bhi(qv.y);
  float qf4 = blo(qv.z), qf5 = bhi(qv.z), qf6 = blo(qv.w), qf7 = bhi(qv.w);
  float sc0 = T.p0[h] * 0.25f, sc1 = T.p1[h] * 0.25f;

  int e0 = starts[wid], e1 = starts[wid + 1];
  float lsum = 0.f;
  float a0 = 0.f, a1 = 0.f, a2 = 0.f, a3 = 0.f, a4 = 0.f, a5 = 0.f, a6 = 0.f, a7 = 0.f;

  for (int eb = e0; eb < e1; eb += 8) {
    int eA = eb + g, eB = eb + 4 + g;
    bool actA = eA < e1, actB = eB < e1;
    int pA = payload[actA ? eA : e0];
    int pB = payload[actB ? eB : e0];
    int sA = pA & 0x0FFFFFFF, slA = pA >> 28;
    int sB = pB & 0x0FFFFFFF, slB = pB >> 28;
    const ushort* kbA = slA ? T.k1 : T.k0;
    const ushort* vbA = slA ? T.v1 : T.v0;
    const ushort* kbB = slB ? T.k1 : T.k0;
    const ushort* vbB = slB ? T.v1 : T.v0;
    size_t roA = (size_t)sA * (slA ? T.ld1 : T.ld0) + l * 8;
    size_t roB = (size_t)sB * (slB ? T.ld1 : T.ld0) + l * 8;
    uint4 kA = *(const uint4*)(kbA + roA);
    uint4 vA = *(const uint4*)(vbA + roA);
    uint4 kB = *(const uint4*)(kbB + roB);
    uint4 vB = *(const uint4*)(vbB + roB);

    float pa = qf0 * blo(kA.x) + qf1 * bhi(kA.x) + qf2 * blo(kA.y) + qf3 * bhi(kA.y)
             + qf4 * blo(kA.z) + qf5 * bhi(kA.z) + qf6 * blo(kA.w) + qf7 * bhi(kA.w);
    float pb = qf0 * blo(kB.x) + qf1 * bhi(kB.x) + qf2 * blo(kB.y) + qf3 * bhi(kB.y)
             + qf4 * blo(kB.z) + qf5 * bhi(kB.z) + qf6 * blo(kB.w) + qf7 * bhi(kB.w);
    pa += __shfl_xor(pa, 1, 64);
    pb += __shfl_xor(pb, 1, 64);
    float exA = __expf(fminf(pa * (slA ? sc1 : sc0), 80.f));
    float exB = __expf(fminf(pb * (slB ? sc1 : sc0), 80.f));
    exA = actA ? exA : 0.f;
    exB = actB ? exB : 0.f;
    lsum += exA + exB;
    a0 += exA * blo(vA.x) + exB * blo(vB.x);
    a1 += exA * bhi(vA.x) + exB * bhi(vB.x);
    a2 += exA * blo(vA.y) + exB * blo(vB.y);
    a3 += exA * bhi(vA.y) + exB * bhi(vB.y);
    a4 += exA * blo(vA.z) + exB * blo(vB.z);
    a5 += exA * bhi(vA.z) + exB * bhi(vB.z);
    a6 += exA * blo(vA.w) + exB * blo(vB.w);
    a7 += exA * bhi(vA.w) + exB * bhi(vB.w);
  }

  // merge the 4 edge-groups (lanes differ in bits 4,5)
  lsum += __shfl_xor(lsum, 16, 64); lsum += __shfl_xor(lsum, 32, 64);
  a0 += __shfl_xor(a0, 16, 64); a0 += __shfl_xor(a0, 32, 64);
  a1 += __shfl_xor(a1, 16, 64); a1 += __shfl_xor(a1, 32, 64);
  a2 += __shfl_xor(a2, 16, 64); a2 += __shfl_xor(a2, 32, 64);
  a3 += __shfl_xor(a3, 16, 64); a3 += __shfl_xor(a3, 32, 64);
  a4 += __shfl_xor(a4, 16, 64); a4 += __shfl_xor(a4, 32, 64);
  a5 += __shfl_xor(a5, 16, 64); a5 += __shfl_xor(a5, 32, 64);
  a6 += __shfl_xor(a6, 16, 64); a6 += __shfl_xor(a6, 32, 64);
  a7 += __shfl_xor(a7, 16, 64); a7 += __shfl_xor(a7, 32, 64);

  if (g == 0) {
    float inv = 1.f / (lsum + 1e-16f);
    float xs[8] = {a0 * inv, a1 * inv, a2 * inv, a3 * inv,
                   a4 * inv, a5 * inv, a6 * inv, a7 * inv};
    uint o[4];
#pragma unroll
    for (int jj = 0; jj < 4; ++jj) {
      float xa = xs[2 * jj], xb = xs[2 * jj + 1];
      float ga = 0.5f * xa * (1.f + erff(xa * 0.70710678118654752f));
      float gb = 0.5f * xb * (1.f + erff(xb * 0.70710678118654752f));
      o[jj] = ((uint)f2b(gb) << 16) | (uint)f2b(ga);
    }
    int tm = d >> 7, row = d & 127;
    int tk = l >> 2, sw = (l & 3) ^ ((row >> 1) & 3);
    size_t us = (((size_t)tm * 4 + tk) * 512 + (size_t)row * 4 + sw) * 8;
    *(uint4*)(T.agg + us) = make_uint4(o[0], o[1], o[2], o[3]);
  }
}

// ================= host =====================================================
extern "C" void kernel_launch(void* const* d_in, const int* in_sizes, int n_in,
                              void* d_out, int out_size, void* d_ws, size_t ws_size,
                              hipStream_t stream)
{
  const float* x_herb = (const float*)d_in[0];
  const float* x_ing  = (const float*)d_in[1];
  const float* x_tgt  = (const float*)d_in[2];
  const float* W_herb = (const float*)d_in[3];
  const float* b_herb = (const float*)d_in[4];
  const float* W_ing  = (const float*)d_in[5];
  const float* b_ing  = (const float*)d_in[6];
  const float* W_tgt  = (const float*)d_in[7];
  const float* b_tgt  = (const float*)d_in[8];
  const float* Wk     = (const float*)d_in[9];
  const float* bk     = (const float*)d_in[10];
  const float* Wq     = (const float*)d_in[11];
  const float* bq     = (const float*)d_in[12];
  const float* Wv     = (const float*)d_in[13];
  const float* bv     = (const float*)d_in[14];
  const float* a_rel  = (const float*)d_in[15];
  const float* m_rel  = (const float*)d_in[16];
  const float* p_rel  = (const float*)d_in[17];
  const float* Wa     = (const float*)d_in[18];
  const float* ba     = (const float*)d_in[19];
  const float* skip   = (const float*)d_in[20];
  const float* W_out  = (const float*)d_in[21];
  const float* b_out  = (const float*)d_in[22];
  const int* srcs[4] = {(const int*)d_in[23], (const int*)d_in[25],
                        (const int*)d_in[27], (const int*)d_in[29]};
  const int* dsts[4] = {(const int*)d_in[24], (const int*)d_in[26],
                        (const int*)d_in[28], (const int*)d_in[30]};

  const int Nh = in_sizes[0] / 400;
  const int Ni = in_sizes[1] / 300;
  const int Nt = in_sizes[2] / 200;
  const int E  = in_sizes[23];
  const int Ntot = Nh + Ni + Nt;

  const int MT_h = (Nh + 127) / 128, MT_i = (Ni + 127) / 128, MT_t = (Nt + 127) / 128;
  const int KT_h = 13, KT_i = 10, KT_t = 7;   // Kpad 416/320/224

  char* base = (char*)d_ws;
  size_t off = 0;
  auto A = [&](size_t bytes) -> void* {
    void* p = base + off; off += (bytes + 255) & ~(size_t)255; return p;
  };
  ushort* xp_h  = (ushort*)A((size_t)MT_h * KT_h * 8192);
  ushort* xp_i  = (ushort*)A((size_t)MT_i * KT_i * 8192);
  ushort* xp_t  = (ushort*)A((size_t)MT_t * KT_t * 8192);
  ushort* xsP_h = (ushort*)A((size_t)MT_h * 4 * 8192);
  ushort* xsP_i = (ushort*)A((size_t)MT_i * 4 * 8192);
  ushort* xsP_t = (ushort*)A((size_t)MT_t * 4 * 8192);
  ushort* fused_h = (ushort*)A((size_t)MT_h * 128 * 384 * 2);  // [q|k0|v0]
  ushort* fused_i = (ushort*)A((size_t)MT_i * 128 * 640 * 2);  // [q|k1|v1|k2|v2]
  ushort* fused_t = (ushort*)A((size_t)MT_t * 128 * 384 * 2);  // [q|k3|v3]
  ushort* aggp_h  = (ushort*)A((size_t)MT_h * 4 * 8192);
  ushort* aggp_i  = (ushort*)A((size_t)MT_i * 4 * 8192);
  ushort* aggp_t  = (ushort*)A((size_t)MT_t * 4 * 8192);
  ushort* htmp_p  = (ushort*)A((size_t)MT_h * 4 * 8192);
  float* Wk_rel = (float*)A(4 * 16384 * 4);
  float* Wv_rel = (float*)A(4 * 16384 * 4);
  float* bk_rel = (float*)A(4 * 128 * 4);
  float* bv_rel = (float*)A(4 * 128 * 4);
  ushort* Weff1_h = (ushort*)A((size_t)KT_h * 8192);
  ushort* Weff1_i = (ushort*)A((size_t)KT_i * 8192);
  ushort* Weff1_t = (ushort*)A((size_t)KT_t * 8192);
  ushort* Wcat_h = (ushort*)A((size_t)3 * 4 * 8192);
  ushort* Wcat_i = (ushort*)A((size_t)5 * 4 * 8192);
  ushort* Wcat_t = (ushort*)A((size_t)3 * 4 * 8192);
  float* bcat   = (float*)A(1408 * 4);
  ushort* Wa_t   = (ushort*)A((size_t)3 * 16384 * 2);
  ushort* Wout_t = (ushort*)A((size_t)16384 * 2);
  int* cnt     = (int*)A((size_t)Ntot * 4);
  int* starts  = (int*)A((size_t)(Ntot + 4) * 4);
  int* cursor  = (int*)A((size_t)Ntot * 4);
  int* bsum    = (int*)A(1024);
  int* payload = (int*)A((size_t)(4 * E + 8) * 4);
  (void)ws_size; (void)n_in;

  const int toff_h = 0, toff_i = Nh, toff_t = Nh + Ni;
  dim3 blk(256);

  // --- 1: prologue (pack x3 + zero cnt + combine_rel) ---
  int sl_h = MT_h * KT_h * 512, sl_i = MT_i * KT_i * 512, sl_t = MT_t * KT_t * 512;
  Prolog P;
  P.pk[0] = {x_herb, xp_h, Nh, 400, KT_h, 0};
  P.pk[1] = {x_ing,  xp_i, Ni, 300, KT_i, sl_h};
  P.pk[2] = {x_tgt,  xp_t, Nt, 200, KT_t, sl_h + sl_i};
  P.zstart = sl_h + sl_i + sl_t;
  P.crwstart = P.zstart + Ntot;
  P.total = P.crwstart + 4 * 2 * 129 * 128;
  P.cnt = cnt;
  P.Wk = Wk; P.bk = bk; P.Wv = Wv; P.bv = bv; P.a_rel = a_rel; P.m_rel = m_rel;
  P.Wk_rel = Wk_rel; P.bk_rel = bk_rel; P.Wv_rel = Wv_rel; P.bv_rel = bv_rel;
  prologue<<<(P.total + 255) / 256, blk, 0, stream>>>(P);

  // --- 2: CSR count + 3-phase scan + scatter ---
  int egrid4 = (4 * E + 255) / 256;
  count_edges<<<egrid4, blk, 0, stream>>>(dsts[0], dsts[1], dsts[2], dsts[3],
                                          toff_i, toff_h, toff_t, toff_i, cnt, E);
  int nb = (Ntot + 1023) / 1024;
  scan_blocks<<<nb, blk, 0, stream>>>(cnt, bsum, Ntot);
  scan_tops<<<1, blk, 0, stream>>>(bsum, nb, starts, Ntot);
  scan_final<<<nb, blk, 0, stream>>>(cnt, bsum, starts, cursor, Ntot);
  scatter_edges<<<egrid4, blk, 0, stream>>>(srcs[0], dsts[0], srcs[1], dsts[1],
                                            srcs[2], dsts[2], srcs[3], dsts[3],
                                            toff_i, toff_h, toff_t, toff_i,
                                            cursor, payload, E);

  // --- 3: weight prep (layout conversion only) ---
  PrepW PW;
  int st = 0;
  PW.b[0] = {W_herb, Weff1_h, 400, st}; st += KT_h * 512;
  PW.b[1] = {W_ing,  Weff1_i, 300, st}; st += KT_i * 512;
  PW.b[2] = {W_tgt,  Weff1_t, 200, st}; st += KT_t * 512;
  const float* csrc[11] = {
      Wq + 0 * 16384, Wk_rel + 0 * 16384, Wv_rel + 0 * 16384,
      Wq + 1 * 16384, Wk_rel + 1 * 16384, Wv_rel + 1 * 16384,
                      Wk_rel + 2 * 16384, Wv_rel + 2 * 16384,
      Wq + 2 * 16384, Wk_rel + 3 * 16384, Wv_rel + 3 * 16384};
  ushort* cdst[11] = {
      Wcat_h, Wcat_h + 16384, Wcat_h + 32768,
      Wcat_i, Wcat_i + 16384, Wcat_i + 32768, Wcat_i + 49152, Wcat_i + 65536,
      Wcat_t, Wcat_t + 16384, Wcat_t + 32768};
  for (int z = 0; z < 11; ++z) { PW.b[3 + z] = {csrc[z], cdst[z], 128, st}; st += 2048; }
  PW.b[14] = {Wa + 0 * 16384, Wa_t + 0 * 16384, 128, st}; st += 2048;
  PW.b[15] = {Wa + 1 * 16384, Wa_t + 1 * 16384, 128, st}; st += 2048;
  PW.b[16] = {Wa + 2 * 16384, Wa_t + 2 * 16384, 128, st}; st += 2048;
  PW.b[17] = {W_out, Wout_t, 128, st}; st += 2048;
  PW.slot_total = st;
  PW.bsrc[0] = bq + 0;   PW.bsrc[1] = bk_rel + 0;   PW.bsrc[2] = bv_rel + 0;
  PW.bsrc[3] = bq + 128; PW.bsrc[4] = bk_rel + 128; PW.bsrc[5] = bv_rel + 128;
                         PW.bsrc[6] = bk_rel + 256; PW.bsrc[7] = bv_rel + 256;
  PW.bsrc[8] = bq + 256; PW.bsrc[9] = bk_rel + 384; PW.bsrc[10] = bv_rel + 384;
  PW.bdst = bcat;
  PW.total = st + 1408;
  prep_weights<<<(PW.total + 255) / 256, blk, 0, stream>>>(PW);

  // --- 4: GEMM1  xs = x @ Win  (packed-A bf16 output) ---
  Gemm3 G1;
  G1.skip = skip; G1.nseg = 3;
  G1.s[0] = {xp_h, Weff1_h, b_herb, xsP_h, nullptr, KT_h, 0, 0, 0, 4, 1, 0};
  G1.s[1] = {xp_i, Weff1_i, b_ing,  xsP_i, nullptr, KT_i, 0, 0, 0, 4, 1, MT_h};
  G1.s[2] = {xp_t, Weff1_t, b_tgt,  xsP_t, nullptr, KT_t, 0, 0, 0, 4, 1, MT_h + MT_i};
  gemm_sched<<<MT_h + MT_i + MT_t, blk, 0, stream>>>(G1);

  // --- 5: GEMM2  [q|k|v] = xs @ Wcat (row-major bf16 fused output) ---
  Gemm3 G2;
  G2.skip = skip; G2.nseg = 3;
  G2.s[0] = {xsP_h, Wcat_h, bcat + 0,    fused_h, nullptr, 4, 384, 0, 0, 0, 3, 0};
  G2.s[1] = {xsP_i, Wcat_i, bcat + 384,  fused_i, nullptr, 4, 640, 0, 0, 0, 5, MT_h * 3};
  G2.s[2] = {xsP_t, Wcat_t, bcat + 1024, fused_t, nullptr, 4, 384, 0, 0, 0, 3,
             MT_h * 3 + MT_i * 5};
  gemm_sched<<<MT_h * 3 + MT_i * 5 + MT_t * 3, blk, 0, stream>>>(G2);

  // --- 6: gather attention (all types, one wave per node) ---
  GatherDesc GD;
  GD.n0 = Nh; GD.n1 = Nh + Ni;
  GD.ty[0] = {fused_h, fused_i + 128, fused_i + 256, fused_i + 128, fused_i + 256,
              p_rel + 1 * 8, p_rel + 1 * 8, aggp_h, 384, 640, 640};
  GD.ty[1] = {fused_i, fused_h + 128, fused_h + 256, fused_t + 128, fused_t + 256,
              p_rel + 0 * 8, p_rel + 3 * 8, aggp_i, 640, 384, 384};
  GD.ty[2] = {fused_t, fused_i + 384, fused_i + 512, fused_i + 384, fused_i + 512,
              p_rel + 2 * 8, p_rel + 2 * 8, aggp_t, 384, 640, 640};
  gather_all<<<(Ntot + 3) / 4, blk, 0, stream>>>(starts, payload, GD, Ntot);

  // --- 7: fused epilogue GEMMs (Wa per type; skip from packed xs) ---
  float* outp = (float*)d_out;
  float* out_herb = outp;
  float* out_ing  = outp + (size_t)Nh * HID;
  float* out_tgt  = outp + (size_t)(Nh + Ni) * HID;
  Gemm3 GE;
  GE.skip = skip; GE.nseg = 3;
  GE.s[0] = {aggp_h, Wa_t + 0 * 16384, ba + 0 * 128, htmp_p, xsP_h,
             4, 0, 0, 0, 3, 1, 0};
  GE.s[1] = {aggp_i, Wa_t + 1 * 16384, ba + 1 * 128, out_ing, xsP_i,
             4, 128, Ni, 1, 2, 1, MT_h};
  GE.s[2] = {aggp_t, Wa_t + 2 * 16384, ba + 2 * 128, out_tgt, xsP_t,
             4, 128, Nt, 2, 2, 1, MT_h + MT_i};
  gemm_sched<<<MT_h + MT_i + MT_t, blk, 0, stream>>>(GE);

  // --- 8: final herb GEMM ---
  Gemm3 GF;
  GF.skip = skip; GF.nseg = 1;
  GF.s[0] = {htmp_p, Wout_t, b_out, out_herb, nullptr, 4, 128, Nh, 0, 1, 1, 0};
  GF.s[1] = GF.s[0]; GF.s[2] = GF.s[0];
  gemm_sched<<<MT_h, blk, 0, stream>>>(GF);
  (void)out_size;
}